// Round 1
// baseline (160.589 us; speedup 1.0000x reference)
//
#include <hip/hip_runtime.h>
#include <hip/hip_bf16.h>

#define NN 4096
#define LOG2E 1.44269504088896340736f

typedef __attribute__((ext_vector_type(8))) short s8v;   // 8 x bf16
typedef __attribute__((ext_vector_type(4))) float f4v;   // mfma accumulator

// packed bf16 conversion, RNE: lo = bf16(a), hi = bf16(b)
__device__ __forceinline__ unsigned cvtpk(float a, float b){
  unsigned r;
  asm("v_cvt_pk_bf16_f32 %0, %1, %2" : "=v"(r) : "v"(a), "v"(b));
  return r;
}

// Kernel 1: h = x@W (fp32), write Vf in MFMA-fragment order (bf16),
// el' (x LOG2E) and factorized exponentials Qr=exp2(er'), Sr=exp2(0.2*er').
// x rows are read with WAVE-UNIFORM addresses -> scalar (s_load) pipe,
// no LDS at all; W loads keep the depth-2 software pipeline.
__global__ __launch_bounds__(256) void k1_proj(
    const float* __restrict__ x, const float* __restrict__ W,
    const float* __restrict__ a, unsigned short* __restrict__ Vf,
    float* __restrict__ el4, float* __restrict__ Qr, float* __restrict__ Sr)
{
  const int t = threadIdx.x;
  const int r0 = blockIdx.x * 8;
  const float* xb = x + (size_t)r0 * 256;

  float acc[8] = {0.f,0.f,0.f,0.f,0.f,0.f,0.f,0.f};
  const float* Wp = W + t;             // column c = t
  float wa0 = Wp[0],    wa1 = Wp[256],  wa2 = Wp[512],  wa3 = Wp[768];
  float wb0 = Wp[1024], wb1 = Wp[1280], wb2 = Wp[1536], wb3 = Wp[1792];

  // depth-1 prefetch of the (uniform) x values: 8 rows x float4 = 32 SGPRs
  float4 xc[8];
  #pragma unroll
  for (int r = 0; r < 8; ++r) xc[r] = *(const float4*)(xb + r * 256);

  #pragma unroll 1
  for (int k4 = 0; k4 < 64; ++k4) {
    const int kn = (k4 + 2) & 63;      // depth-2 W prefetch, wrap stays in-bounds
    float nw0 = Wp[kn*1024 +   0];
    float nw1 = Wp[kn*1024 + 256];
    float nw2 = Wp[kn*1024 + 512];
    float nw3 = Wp[kn*1024 + 768];
    const int kx = (k4 + 1) & 63;      // depth-1 x prefetch
    float4 xn[8];
    #pragma unroll
    for (int r = 0; r < 8; ++r) xn[r] = *(const float4*)(xb + r * 256 + kx * 4);
    #pragma unroll
    for (int r = 0; r < 8; ++r) {
      acc[r] = fmaf(xc[r].x, wa0, acc[r]);
      acc[r] = fmaf(xc[r].y, wa1, acc[r]);
      acc[r] = fmaf(xc[r].z, wa2, acc[r]);
      acc[r] = fmaf(xc[r].w, wa3, acc[r]);
    }
    #pragma unroll
    for (int r = 0; r < 8; ++r) xc[r] = xn[r];
    wa0 = wb0; wa1 = wb1; wa2 = wb2; wa3 = wb3;
    wb0 = nw0; wb1 = nw1; wb2 = nw2; wb3 = nw3;
  }

  // Vf write: thread t holds V[r0..r0+7][c=t] -> exactly one fragment chunk
  union { unsigned u[4]; s8v v; } pk;
  #pragma unroll
  for (int p = 0; p < 4; ++p)
    pk.u[p] = cvtpk(acc[2*p], acc[2*p+1]);
  {
    const int hh = t >> 6, nf = (t >> 4) & 3, mm = t & 15;
    const int jblk = r0 >> 5, qq = (r0 >> 3) & 3;
    const size_t chunk = (size_t)(((hh * 128 + jblk) * 4 + nf) * 64 + qq * 16 + mm);
    *(s8v*)(Vf + chunk * 8) = pk.v;
  }

  // el/er: wave w == head h; lane f = t&63
  const int f = t & 63, h = t >> 6;
  const float al = a[f], ar = a[64 + f];
  #pragma unroll
  for (int r = 0; r < 8; ++r) {
    float v = acc[r] * al;
    float u = acc[r] * ar;
    #pragma unroll
    for (int off = 32; off > 0; off >>= 1) {
      v += __shfl_xor(v, off);
      u += __shfl_xor(u, off);
    }
    if (f == 0) {
      el4[(r0 + r) * 4 + h] = v * LOG2E;                     // [i][h] (x LOG2E)
      float up = u * LOG2E;
      Qr[h * NN + (r0 + r)] = __builtin_amdgcn_exp2f(up);        // [h][j]
      Sr[h * NN + (r0 + r)] = __builtin_amdgcn_exp2f(0.2f * up); // [h][j]
    }
  }
}

// Kernel 0: pack adj to bits AND softmax-denominator partials, 4 windows per
// block. grid (1024 row-groups, 4 window-groups), block 256 = 4 waves;
// wave = 1 row x 4 windows -> 4 independent adj float4 HBM loads in flight.
// Q/S for the 4 windows staged once in LDS (32 KB). One reduction per wave.
// Ballot order per 256-j window: bit for j in word (j&3) at position (j>>2).
// lsumP[p4][row][h] written with plain stores (no atomics, no memset).
__global__ __launch_bounds__(256, 4) void k0_pack(
    const float* __restrict__ adj, const float* __restrict__ el4,
    const float* __restrict__ Qr, const float* __restrict__ Sr,
    unsigned long long* __restrict__ adjB, float* __restrict__ lsumP)
{
  __shared__ float qsh[8192];          // 32KB: [k(4)][{Q,S}][h(4)][256]
  const int t = threadIdx.x;
  const int w = t >> 6, l = t & 63;
  const int row = blockIdx.x * 4 + w;
  const int p4 = blockIdx.y;
  const int jbase = p4 * 1024;

  // issue the 4 HBM adj loads first (deep MLP)
  const float* arow = adj + (size_t)row * NN + jbase + l * 4;
  float4 av0 = *(const float4*)(arow);
  float4 av1 = *(const float4*)(arow + 256);
  float4 av2 = *(const float4*)(arow + 512);
  float4 av3 = *(const float4*)(arow + 768);

  // cooperative stage: thread (h = t>>6, lane l), 4 windows x {Q,S}
  {
    const int h = t >> 6;
    #pragma unroll
    for (int k = 0; k < 4; ++k) {
      float4 qv = *(const float4*)(Qr + h * NN + jbase + k * 256 + l * 4);
      float4 sv = *(const float4*)(Sr + h * NN + jbase + k * 256 + l * 4);
      *(float4*)(qsh + ((k * 2 + 0) * 4 + h) * 256 + l * 4) = qv;
      *(float4*)(qsh + ((k * 2 + 1) * 4 + h) * 256 + l * 4) = sv;
    }
  }

  // pack bits (window = p4*4 + k)
  {
    unsigned long long* dst = adjB + (size_t)row * 64 + p4 * 16;
    const float4 avs[4] = {av0, av1, av2, av3};
    #pragma unroll
    for (int k = 0; k < 4; ++k) {
      unsigned long long b0 = __ballot(avs[k].x != 0.0f);
      unsigned long long b1 = __ballot(avs[k].y != 0.0f);
      unsigned long long b2 = __ballot(avs[k].z != 0.0f);
      unsigned long long b3 = __ballot(avs[k].w != 0.0f);
      if (l == 0) {
        dst[k * 4 + 0] = b0; dst[k * 4 + 1] = b1;
        dst[k * 4 + 2] = b2; dst[k * 4 + 3] = b3;
      }
    }
  }

  // P,R for this row (wave-uniform)
  float4 elv = *(const float4*)(el4 + row * 4);
  const float P[4] = { __builtin_amdgcn_exp2f(elv.x), __builtin_amdgcn_exp2f(elv.y),
                       __builtin_amdgcn_exp2f(elv.z), __builtin_amdgcn_exp2f(elv.w) };
  const float R[4] = { __builtin_amdgcn_exp2f(0.2f*elv.x), __builtin_amdgcn_exp2f(0.2f*elv.y),
                       __builtin_amdgcn_exp2f(0.2f*elv.z), __builtin_amdgcn_exp2f(0.2f*elv.w) };

  __syncthreads();

  float ls[4] = {0.f, 0.f, 0.f, 0.f};
  {
    const float4 avs[4] = {av0, av1, av2, av3};
    #pragma unroll
    for (int k = 0; k < 4; ++k) {
      const float4 av = avs[k];
      #pragma unroll
      for (int h = 0; h < 4; ++h) {
        float4 qv = *(const float4*)(qsh + ((k * 2 + 0) * 4 + h) * 256 + l * 4);
        float4 sv = *(const float4*)(qsh + ((k * 2 + 1) * 4 + h) * 256 + l * 4);
        float s;
        s = av.x * fmaxf(P[h] * qv.x, R[h] * sv.x);
        s = fmaf(av.y, fmaxf(P[h] * qv.y, R[h] * sv.y), s);
        s = fmaf(av.z, fmaxf(P[h] * qv.z, R[h] * sv.z), s);
        s = fmaf(av.w, fmaxf(P[h] * qv.w, R[h] * sv.w), s);
        ls[h] += s;
      }
    }
  }
  #pragma unroll
  for (int h = 0; h < 4; ++h) {
    float v = ls[h];
    #pragma unroll
    for (int off = 32; off > 0; off >>= 1) v += __shfl_xor(v, off);
    ls[h] = v;
  }
  if (l == 0)
    *(float4*)(lsumP + ((size_t)p4 * NN + row) * 4) = make_float4(ls[0], ls[1], ls[2], ls[3]);
}

// Kernel 2: masked-softmax-weighted PV via MFMA, heads folded, 32 rows/wave.
// grid (128 i-tiles of 32 rows, 4 splits), block 256 = 4 waves; wave w owns
// window sw = blockIdx.y*4 + w and BOTH 16-row sub-tiles -> every B-frag and
// every LDS Q/S read is reused for 2 sub-tiles (halves Vf L2 traffic).
// LDS merge across the 4 windows; wave 0 does the atomics (4/cell).
// lane: m = l&15 (row in sub-tile), q = l>>4 (k-quad).
__global__ __launch_bounds__(256, 2) void k2_attn(
    const unsigned long long* __restrict__ adjB, const unsigned short* __restrict__ Vf,
    const float* __restrict__ el4, const float* __restrict__ lsumP,
    const float* __restrict__ Qr, const float* __restrict__ Sr,
    float* __restrict__ out)
{
  __shared__ float qs[8192];           // 32KB: [w][h][jc][q][16] {Q[8],S[8]}; reused for merge
  const int t = threadIdx.x;
  const int w = t >> 6, l = t & 63;
  const int m = l & 15, q = l >> 4;
  const int i0 = blockIdx.x * 32;
  const int sw = blockIdx.y * 4 + w;   // this wave's 256-j window (0..15)
  const int jwin = sw * 256;

  // wave-private staging: no barrier needed before use
  {
    const int jc = l >> 3, qq = (l >> 1) & 3, hp = (l & 1) * 4;
    #pragma unroll
    for (int h = 0; h < 4; ++h) {
      float4 qv = *(const float4*)(Qr + h * NN + jwin + l * 4);
      float4 sv = *(const float4*)(Sr + h * NN + jwin + l * 4);
      float* cell = qs + (((w * 4 + h) * 8 + jc) * 4 + qq) * 16;
      *(float4*)(cell + hp) = qv;
      *(float4*)(cell + 8 + hp) = sv;
    }
  }

  // per-sub-tile row params: PL/RL inline from el4 + summed lsumP; masks
  float Pl[2][4], Rl[2][4];
  unsigned long long bm[2][4];
  #pragma unroll
  for (int s = 0; s < 2; ++s) {
    const int i = i0 + s * 16 + m;
    float4 elv = *(const float4*)(el4 + i * 4);
    float lx = 0.f, ly = 0.f, lz = 0.f, lw = 0.f;
    #pragma unroll
    for (int p = 0; p < 4; ++p) {
      float4 v = *(const float4*)(lsumP + ((size_t)p * NN + i) * 4);
      lx += v.x; ly += v.y; lz += v.z; lw += v.w;
    }
    const float el_[4] = {elv.x, elv.y, elv.z, elv.w};
    const float lv_[4] = {lx, ly, lz, lw};
    #pragma unroll
    for (int h = 0; h < 4; ++h) {
      const float inv = 1.0f / lv_[h];   // > 0: diagonal of adj is 1
      Pl[s][h] = __builtin_amdgcn_exp2f(el_[h]) * inv;
      Rl[s][h] = __builtin_amdgcn_exp2f(0.2f * el_[h]) * inv;
    }
    const unsigned long long* bp = adjB + (size_t)i * 64 + sw * 4;
    bm[s][0] = bp[0]; bm[s][1] = bp[1]; bm[s][2] = bp[2]; bm[s][3] = bp[3];
  }

  f4v acc[2][4];
  #pragma unroll
  for (int s = 0; s < 2; ++s)
    #pragma unroll
    for (int nf = 0; nf < 4; ++nf) acc[s][nf] = (f4v){0.f, 0.f, 0.f, 0.f};

  const s8v* vfp = (const s8v*)Vf;
  s8v Bc[4];
  #pragma unroll
  for (int nf = 0; nf < 4; ++nf)
    Bc[nf] = vfp[(size_t)((0 * 128 + sw * 8 + 0) * 4 + nf) * 64 + l];

  #pragma unroll 1
  for (int jc = 0; jc < 8; ++jc) {
    const unsigned sh = jc * 8 + q * 2;
    float bitf[2][8];
    #pragma unroll
    for (int s = 0; s < 2; ++s) {
      const unsigned t0 = (unsigned)(bm[s][0] >> sh) & 3u;
      const unsigned t1 = (unsigned)(bm[s][1] >> sh) & 3u;
      const unsigned t2 = (unsigned)(bm[s][2] >> sh) & 3u;
      const unsigned t3 = (unsigned)(bm[s][3] >> sh) & 3u;
      bitf[s][0] = (float)(t0 & 1u); bitf[s][4] = (float)(t0 >> 1);
      bitf[s][1] = (float)(t1 & 1u); bitf[s][5] = (float)(t1 >> 1);
      bitf[s][2] = (float)(t2 & 1u); bitf[s][6] = (float)(t2 >> 1);
      bitf[s][3] = (float)(t3 & 1u); bitf[s][7] = (float)(t3 >> 1);
    }

    #pragma unroll
    for (int h = 0; h < 4; ++h) {
      const int hn = (h < 3) ? h + 1 : 0;
      const int jcn = (h < 3) ? jc : jc + 1;
      s8v Bn[4];
      #pragma unroll
      for (int nf = 0; nf < 4; ++nf)
        Bn[nf] = vfp[(size_t)((hn * 128 + sw * 8 + jcn) * 4 + nf) * 64 + l];

      const float* cell = qs + (((w * 4 + h) * 8 + jc) * 4 + q) * 16;
      float4 q0  = *(const float4*)(cell);
      float4 q1  = *(const float4*)(cell + 4);
      float4 sv0 = *(const float4*)(cell + 8);
      float4 sv1 = *(const float4*)(cell + 12);
      #pragma unroll
      for (int s = 0; s < 2; ++s) {
        const float Ph = Pl[s][h], Rh = Rl[s][h];
        float s0 = bitf[s][0] * fmaxf(Ph * q0.x, Rh * sv0.x);
        float s1 = bitf[s][1] * fmaxf(Ph * q0.y, Rh * sv0.y);
        float s2 = bitf[s][2] * fmaxf(Ph * q0.z, Rh * sv0.z);
        float s3 = bitf[s][3] * fmaxf(Ph * q0.w, Rh * sv0.w);
        float s4 = bitf[s][4] * fmaxf(Ph * q1.x, Rh * sv1.x);
        float s5 = bitf[s][5] * fmaxf(Ph * q1.y, Rh * sv1.y);
        float s6 = bitf[s][6] * fmaxf(Ph * q1.z, Rh * sv1.z);
        float s7 = bitf[s][7] * fmaxf(Ph * q1.w, Rh * sv1.w);
        union { unsigned u[4]; s8v v; } A;   // A-frag: row m, k = q*8+idx
        A.u[0] = cvtpk(s0, s1);
        A.u[1] = cvtpk(s2, s3);
        A.u[2] = cvtpk(s4, s5);
        A.u[3] = cvtpk(s6, s7);
        #pragma unroll
        for (int nf = 0; nf < 4; ++nf)
          acc[s][nf] = __builtin_amdgcn_mfma_f32_16x16x32_bf16(A.v, Bc[nf], acc[s][nf], 0, 0, 0);
      }
      #pragma unroll
      for (int nf = 0; nf < 4; ++nf) Bc[nf] = Bn[nf];
    }
  }

  // merge 4 windows' accs in LDS (stride 36 floats, 16B aligned)
  __syncthreads();                     // all qs reads done
  if (w > 0) {
    float* dst = qs + ((w - 1) * 64 + l) * 36;
    #pragma unroll
    for (int s = 0; s < 2; ++s)
      #pragma unroll
      for (int nf = 0; nf < 4; ++nf)
        *(f4v*)(dst + (s * 4 + nf) * 4) = acc[s][nf];
  }
  __syncthreads();
  if (w == 0) {
    #pragma unroll
    for (int s = 0; s < 2; ++s)
      #pragma unroll
      for (int nf = 0; nf < 4; ++nf) {
        f4v sum = acc[s][nf];
        #pragma unroll
        for (int ww = 0; ww < 3; ++ww)
          sum += *(const f4v*)(qs + (ww * 64 + l) * 36 + (s * 4 + nf) * 4);
        #pragma unroll
        for (int r = 0; r < 4; ++r) {
          int row = i0 + s * 16 + q * 4 + r;
          int col = nf * 16 + m;
          atomicAdd(&out[row * 64 + col], 0.25f * sum[r]);
        }
      }
  }
}

extern "C" void kernel_launch(void* const* d_in, const int* in_sizes, int n_in,
                              void* d_out, int out_size, void* d_ws, size_t ws_size,
                              hipStream_t stream) {
  const float* x   = (const float*)d_in[0];   // (4096, 256)
  const float* adj = (const float*)d_in[1];   // (4096, 4096)
  const float* W   = (const float*)d_in[2];   // (256, 256)
  const float* a   = (const float*)d_in[3];   // (128, 1)
  float* out = (float*)d_out;                 // (4096, 64)

  char* ws = (char*)d_ws;
  unsigned short* Vf = (unsigned short*)ws;                  // 2 MB  bf16 fragment-ordered
  float* el4   = (float*)(ws + (2u << 20));                  // 64 KB [4096][4]
  float* Qr    = (float*)(ws + (2u << 20) + (64u << 10));    // 64 KB [4][4096]
  float* Sr    = (float*)(ws + (2u << 20) + (128u << 10));   // 64 KB [4][4096]
  float* lsumP = (float*)(ws + (2u << 20) + (192u << 10));   // 256 KB [4][4096][4]
  unsigned long long* adjB = (unsigned long long*)(ws + (2u << 20) + (448u << 10)); // 2 MB bits

  hipMemsetAsync(out, 0, (size_t)out_size * sizeof(float), stream);
  k1_proj<<<512, 256, 0, stream>>>(x, W, a, Vf, el4, Qr, Sr);
  k0_pack<<<dim3(1024, 4), 256, 0, stream>>>(adj, el4, Qr, Sr, adjB, lsumP);
  k2_attn<<<dim3(128, 4), 256, 0, stream>>>(adjB, Vf, el4, lsumP, Qr, Sr, out);
}

// Round 2
// 156.966 us; speedup vs baseline: 1.0231x; 1.0231x over previous
//
#include <hip/hip_runtime.h>
#include <hip/hip_bf16.h>

#define NN 4096
#define LOG2E 1.44269504088896340736f

typedef __attribute__((ext_vector_type(8))) short s8v;   // 8 x bf16
typedef __attribute__((ext_vector_type(4))) float f4v;   // mfma accumulator

__device__ __forceinline__ unsigned fu(float x){ union{float f;unsigned u;}z; z.f=x; return z.u; }
__device__ __forceinline__ unsigned short f2bf_rne(float x){
  unsigned u = fu(x);
  u += 0x7fffu + ((u >> 16) & 1u);
  return (unsigned short)(u >> 16);
}
__device__ __forceinline__ unsigned pack2_rne(float a, float b){
  return (unsigned)f2bf_rne(a) | ((unsigned)f2bf_rne(b) << 16);
}
// packed bf16 conversion, RNE (same rounding as pack2_rne for finite inputs)
__device__ __forceinline__ unsigned cvtpk(float a, float b){
  unsigned r;
  asm("v_cvt_pk_bf16_f32 %0, %1, %2" : "=v"(r) : "v"(a), "v"(b));
  return r;
}
// async global->LDS, 16B per lane; lds dest is wave-uniform base + lane*16
__device__ __forceinline__ void gload_lds16(const void* g, void* lds){
  __builtin_amdgcn_global_load_lds((const __attribute__((address_space(1))) unsigned*)g,
                                   (__attribute__((address_space(3))) unsigned*)lds, 16, 0, 0);
}

// Kernel 1: h = x@W (fp32), write Vf in MFMA-fragment order (bf16),
// el' (x LOG2E) and factorized exponentials Qr=exp2(er'), Sr=exp2(0.2*er').
// W loads: depth-2 software pipeline. (round-0 measured-best version)
__global__ __launch_bounds__(256) void k1_proj(
    const float* __restrict__ x, const float* __restrict__ W,
    const float* __restrict__ a, unsigned short* __restrict__ Vf,
    float* __restrict__ el4, float* __restrict__ Qr, float* __restrict__ Sr)
{
  __shared__ float4 xs[512];           // 8 rows x 256 cols fp32
  const int t = threadIdx.x;
  const int r0 = blockIdx.x * 8;
  const float4* xg = (const float4*)(x + (size_t)r0 * 256);
  xs[t] = xg[t];
  xs[t + 256] = xg[t + 256];
  __syncthreads();

  float acc[8] = {0.f,0.f,0.f,0.f,0.f,0.f,0.f,0.f};
  const float* Wp = W + t;             // column c = t
  float wa0 = Wp[0],    wa1 = Wp[256],  wa2 = Wp[512],  wa3 = Wp[768];
  float wb0 = Wp[1024], wb1 = Wp[1280], wb2 = Wp[1536], wb3 = Wp[1792];
  #pragma unroll 1
  for (int k4 = 0; k4 < 64; ++k4) {
    const int kn = (k4 + 2) & 63;      // depth-2 prefetch, wrap stays in-bounds
    float nw0 = Wp[kn*1024 +   0];
    float nw1 = Wp[kn*1024 + 256];
    float nw2 = Wp[kn*1024 + 512];
    float nw3 = Wp[kn*1024 + 768];
    #pragma unroll
    for (int r = 0; r < 8; ++r) {
      float4 xv = xs[r*64 + k4];       // broadcast LDS read
      acc[r] = fmaf(xv.x, wa0, acc[r]);
      acc[r] = fmaf(xv.y, wa1, acc[r]);
      acc[r] = fmaf(xv.z, wa2, acc[r]);
      acc[r] = fmaf(xv.w, wa3, acc[r]);
    }
    wa0 = wb0; wa1 = wb1; wa2 = wb2; wa3 = wb3;
    wb0 = nw0; wb1 = nw1; wb2 = nw2; wb3 = nw3;
  }

  // Vf write: thread t holds V[r0..r0+7][c=t] -> exactly one fragment chunk
  union { unsigned u[4]; s8v v; } pk;
  #pragma unroll
  for (int p = 0; p < 4; ++p)
    pk.u[p] = pack2_rne(acc[2*p], acc[2*p+1]);
  {
    const int hh = t >> 6, nf = (t >> 4) & 3, mm = t & 15;
    const int jblk = r0 >> 5, qq = (r0 >> 3) & 3;
    const size_t chunk = (size_t)(((hh * 128 + jblk) * 4 + nf) * 64 + qq * 16 + mm);
    *(s8v*)(Vf + chunk * 8) = pk.v;
  }

  // el/er: wave w == head h; lane f = t&63
  const int f = t & 63, h = t >> 6;
  const float al = a[f], ar = a[64 + f];
  #pragma unroll
  for (int r = 0; r < 8; ++r) {
    float v = acc[r] * al;
    float u = acc[r] * ar;
    #pragma unroll
    for (int off = 32; off > 0; off >>= 1) {
      v += __shfl_xor(v, off);
      u += __shfl_xor(u, off);
    }
    if (f == 0) {
      el4[(r0 + r) * 4 + h] = v * LOG2E;                     // [i][h] (x LOG2E)
      float up = u * LOG2E;
      Qr[h * NN + (r0 + r)] = __builtin_amdgcn_exp2f(up);        // [h][j]
      Sr[h * NN + (r0 + r)] = __builtin_amdgcn_exp2f(0.2f * up); // [h][j]
    }
  }
}

// Kernel 0: pack adj to bits AND softmax-denominator partials, 4 windows per
// block. grid (1024 row-groups, 4 window-groups), block 256 = 4 waves;
// wave = 1 row x 4 windows -> 4 independent adj float4 HBM loads in flight.
// Q/S for the 4 windows staged once in LDS (32 KB). One reduction per wave.
// Ballot order per 256-j window: bit for j in word (j&3) at position (j>>2).
// lsumP[p4][row][h] written with plain stores (no atomics, no memset).
__global__ __launch_bounds__(256, 4) void k0_pack(
    const float* __restrict__ adj, const float* __restrict__ el4,
    const float* __restrict__ Qr, const float* __restrict__ Sr,
    unsigned long long* __restrict__ adjB, float* __restrict__ lsumP)
{
  __shared__ float qsh[8192];          // 32KB: [k(4)][{Q,S}][h(4)][256]
  const int t = threadIdx.x;
  const int w = t >> 6, l = t & 63;
  const int row = blockIdx.x * 4 + w;
  const int p4 = blockIdx.y;
  const int jbase = p4 * 1024;

  // issue the 4 HBM adj loads first (deep MLP)
  const float* arow = adj + (size_t)row * NN + jbase + l * 4;
  float4 av0 = *(const float4*)(arow);
  float4 av1 = *(const float4*)(arow + 256);
  float4 av2 = *(const float4*)(arow + 512);
  float4 av3 = *(const float4*)(arow + 768);

  // cooperative stage: thread (h = t>>6, lane l), 4 windows x {Q,S}
  {
    const int h = t >> 6;
    #pragma unroll
    for (int k = 0; k < 4; ++k) {
      float4 qv = *(const float4*)(Qr + h * NN + jbase + k * 256 + l * 4);
      float4 sv = *(const float4*)(Sr + h * NN + jbase + k * 256 + l * 4);
      *(float4*)(qsh + ((k * 2 + 0) * 4 + h) * 256 + l * 4) = qv;
      *(float4*)(qsh + ((k * 2 + 1) * 4 + h) * 256 + l * 4) = sv;
    }
  }

  // pack bits (window = p4*4 + k)
  {
    unsigned long long* dst = adjB + (size_t)row * 64 + p4 * 16;
    const float4 avs[4] = {av0, av1, av2, av3};
    #pragma unroll
    for (int k = 0; k < 4; ++k) {
      unsigned long long b0 = __ballot(avs[k].x != 0.0f);
      unsigned long long b1 = __ballot(avs[k].y != 0.0f);
      unsigned long long b2 = __ballot(avs[k].z != 0.0f);
      unsigned long long b3 = __ballot(avs[k].w != 0.0f);
      if (l == 0) {
        dst[k * 4 + 0] = b0; dst[k * 4 + 1] = b1;
        dst[k * 4 + 2] = b2; dst[k * 4 + 3] = b3;
      }
    }
  }

  // P,R for this row (wave-uniform)
  float4 elv = *(const float4*)(el4 + row * 4);
  const float P[4] = { __builtin_amdgcn_exp2f(elv.x), __builtin_amdgcn_exp2f(elv.y),
                       __builtin_amdgcn_exp2f(elv.z), __builtin_amdgcn_exp2f(elv.w) };
  const float R[4] = { __builtin_amdgcn_exp2f(0.2f*elv.x), __builtin_amdgcn_exp2f(0.2f*elv.y),
                       __builtin_amdgcn_exp2f(0.2f*elv.z), __builtin_amdgcn_exp2f(0.2f*elv.w) };

  __syncthreads();

  float ls[4] = {0.f, 0.f, 0.f, 0.f};
  {
    const float4 avs[4] = {av0, av1, av2, av3};
    #pragma unroll
    for (int k = 0; k < 4; ++k) {
      const float4 av = avs[k];
      #pragma unroll
      for (int h = 0; h < 4; ++h) {
        float4 qv = *(const float4*)(qsh + ((k * 2 + 0) * 4 + h) * 256 + l * 4);
        float4 sv = *(const float4*)(qsh + ((k * 2 + 1) * 4 + h) * 256 + l * 4);
        float s;
        s = av.x * fmaxf(P[h] * qv.x, R[h] * sv.x);
        s = fmaf(av.y, fmaxf(P[h] * qv.y, R[h] * sv.y), s);
        s = fmaf(av.z, fmaxf(P[h] * qv.z, R[h] * sv.z), s);
        s = fmaf(av.w, fmaxf(P[h] * qv.w, R[h] * sv.w), s);
        ls[h] += s;
      }
    }
  }
  #pragma unroll
  for (int h = 0; h < 4; ++h) {
    float v = ls[h];
    #pragma unroll
    for (int off = 32; off > 0; off >>= 1) v += __shfl_xor(v, off);
    ls[h] = v;
  }
  if (l == 0)
    *(float4*)(lsumP + ((size_t)p4 * NN + row) * 4) = make_float4(ls[0], ls[1], ls[2], ls[3]);
}

// Kernel 2: masked-softmax-weighted PV via MFMA, heads folded.
// NEW: grid (32, 16) -> block = 4 waves ALL on window sw = blockIdx.y;
// wave w owns rows [bx*128 + w*32, +32) (2 x 16-row sub-tiles).
// Vf window slice (128 KB) staged cooperatively via global_load_lds in
// 4 pieces of 32 KB (axis: jc-pair x all h; wave w stages the h=w part),
// double-buffered with counted vmcnt(8) -> Vf L2 traffic drops 4x.
// Q/S stage = 8 KB, written redundantly by every wave (identical values,
// no barrier needed). No cross-window merge: each wave atomics its rows.
// lane: m = l&15 (row in sub-tile), q = l>>4 (k-quad).
__global__ __launch_bounds__(256, 2) void k2_attn(
    const unsigned long long* __restrict__ adjB, const unsigned short* __restrict__ Vf,
    const float* __restrict__ el4, const float* __restrict__ lsumP,
    const float* __restrict__ Qr, const float* __restrict__ Sr,
    float* __restrict__ out)
{
  __shared__ float smem[2048 + 2 * 8192];  // 8KB QS + 2x32KB Vf dbuf = 72KB
  const int t = threadIdx.x;
  const int w = t >> 6, l = t & 63;
  const int m = l & 15, q = l >> 4;
  const int i0 = blockIdx.x * 128 + w * 32;
  const int sw = blockIdx.y;           // this block's 256-j window (0..15)
  const int jwin = sw * 256;

  // QS staging: each wave writes the full 8KB copy (same values) -> no barrier
  {
    const int jc = l >> 3, qq = (l >> 1) & 3, hp = (l & 1) * 4;
    #pragma unroll
    for (int h = 0; h < 4; ++h) {
      float4 qv = *(const float4*)(Qr + h * NN + jwin + l * 4);
      float4 sv = *(const float4*)(Sr + h * NN + jwin + l * 4);
      float* cell = smem + ((h * 8 + jc) * 4 + qq) * 16;
      *(float4*)(cell + hp) = qv;
      *(float4*)(cell + 8 + hp) = sv;
    }
  }

  // per-sub-tile row params: PL/RL inline from el4 + summed lsumP; masks
  float Pl[2][4], Rl[2][4];
  unsigned long long bm[2][4];
  #pragma unroll
  for (int s = 0; s < 2; ++s) {
    const int i = i0 + s * 16 + m;
    float4 elv = *(const float4*)(el4 + i * 4);
    float lx = 0.f, ly = 0.f, lz = 0.f, lw = 0.f;
    #pragma unroll
    for (int p = 0; p < 4; ++p) {
      float4 v = *(const float4*)(lsumP + ((size_t)p * NN + i) * 4);
      lx += v.x; ly += v.y; lz += v.z; lw += v.w;
    }
    const float el_[4] = {elv.x, elv.y, elv.z, elv.w};
    const float lv_[4] = {lx, ly, lz, lw};
    #pragma unroll
    for (int h = 0; h < 4; ++h) {
      const float inv = 1.0f / lv_[h];   // > 0: diagonal of adj is 1
      Pl[s][h] = __builtin_amdgcn_exp2f(el_[h]) * inv;
      Rl[s][h] = __builtin_amdgcn_exp2f(0.2f * el_[h]) * inv;
    }
    const unsigned long long* bp = adjB + (size_t)i * 64 + sw * 4;
    bm[s][0] = bp[0]; bm[s][1] = bp[1]; bm[s][2] = bp[2]; bm[s][3] = bp[3];
  }

  f4v acc[2][4];
  #pragma unroll
  for (int s = 0; s < 2; ++s)
    #pragma unroll
    for (int nf = 0; nf < 4; ++nf) acc[s][nf] = (f4v){0.f, 0.f, 0.f, 0.f};

  // ---- Vf staging: group g covers jc = {2g, 2g+1}, all 4 h (32 KB) ----
  // global 16B-chunk index for (h, sw, jc, nf, lane) = ((h*128+sw*8+jc)*4+nf)*64 + lane
  // wave w stages its h = w piece: chunks [(w*512 + sw*32 + 8g)*64, +512)
  // lds float offset: 2048 + pb*8192 + w*2048 + k*256 + l*4   (matches chunk order)
#define STAGE(gi, pb) { \
    const size_t c0 = ((size_t)(w * 512 + sw * 32 + 8 * (gi))) * 64 + l; \
    float* ldsb = smem + 2048 + (pb) * 8192 + w * 2048 + l * 4; \
    _Pragma("unroll") \
    for (int k = 0; k < 8; ++k) \
      gload_lds16(Vf + (c0 + k * 64) * 8, ldsb + k * 256); \
  }

  STAGE(0, 0);
  STAGE(1, 1);

  #pragma unroll 1
  for (int g = 0; g < 4; ++g) {
    const int pb = g & 1;
    if (g < 3) asm volatile("s_waitcnt vmcnt(8)" ::: "memory");
    else       asm volatile("s_waitcnt vmcnt(0)" ::: "memory");
    __syncthreads();                       // buffer pb (group g) ready everywhere

    #pragma unroll
    for (int jc2 = 0; jc2 < 2; ++jc2) {
      const int jc = 2 * g + jc2;
      const unsigned sh = jc * 8 + q * 2;
      float bitf[2][8];
      #pragma unroll
      for (int s = 0; s < 2; ++s) {
        const unsigned t0 = (unsigned)(bm[s][0] >> sh) & 3u;
        const unsigned t1 = (unsigned)(bm[s][1] >> sh) & 3u;
        const unsigned t2 = (unsigned)(bm[s][2] >> sh) & 3u;
        const unsigned t3 = (unsigned)(bm[s][3] >> sh) & 3u;
        bitf[s][0] = (float)(t0 & 1u); bitf[s][4] = (float)(t0 >> 1);
        bitf[s][1] = (float)(t1 & 1u); bitf[s][5] = (float)(t1 >> 1);
        bitf[s][2] = (float)(t2 & 1u); bitf[s][6] = (float)(t2 >> 1);
        bitf[s][3] = (float)(t3 & 1u); bitf[s][7] = (float)(t3 >> 1);
      }

      #pragma unroll
      for (int h = 0; h < 4; ++h) {
        const float* bfrag = smem + 2048 + pb * 8192 + ((h * 2 + jc2) * 4) * 256 + l * 4;
        s8v B0 = *(const s8v*)(bfrag);
        s8v B1 = *(const s8v*)(bfrag + 256);
        s8v B2 = *(const s8v*)(bfrag + 512);
        s8v B3 = *(const s8v*)(bfrag + 768);

        const float* cell = smem + ((h * 8 + jc) * 4 + q) * 16;
        float4 q0  = *(const float4*)(cell);
        float4 q1  = *(const float4*)(cell + 4);
        float4 sv0 = *(const float4*)(cell + 8);
        float4 sv1 = *(const float4*)(cell + 12);
        #pragma unroll
        for (int s = 0; s < 2; ++s) {
          const float Ph = Pl[s][h], Rh = Rl[s][h];
          float s0 = bitf[s][0] * fmaxf(Ph * q0.x, Rh * sv0.x);
          float s1 = bitf[s][1] * fmaxf(Ph * q0.y, Rh * sv0.y);
          float s2 = bitf[s][2] * fmaxf(Ph * q0.z, Rh * sv0.z);
          float s3 = bitf[s][3] * fmaxf(Ph * q0.w, Rh * sv0.w);
          float s4 = bitf[s][4] * fmaxf(Ph * q1.x, Rh * sv1.x);
          float s5 = bitf[s][5] * fmaxf(Ph * q1.y, Rh * sv1.y);
          float s6 = bitf[s][6] * fmaxf(Ph * q1.z, Rh * sv1.z);
          float s7 = bitf[s][7] * fmaxf(Ph * q1.w, Rh * sv1.w);
          union { unsigned u[4]; s8v v; } A;   // A-frag: row m, k = q*8+idx
          A.u[0] = cvtpk(s0, s1);
          A.u[1] = cvtpk(s2, s3);
          A.u[2] = cvtpk(s4, s5);
          A.u[3] = cvtpk(s6, s7);
          acc[s][0] = __builtin_amdgcn_mfma_f32_16x16x32_bf16(A.v, B0, acc[s][0], 0, 0, 0);
          acc[s][1] = __builtin_amdgcn_mfma_f32_16x16x32_bf16(A.v, B1, acc[s][1], 0, 0, 0);
          acc[s][2] = __builtin_amdgcn_mfma_f32_16x16x32_bf16(A.v, B2, acc[s][2], 0, 0, 0);
          acc[s][3] = __builtin_amdgcn_mfma_f32_16x16x32_bf16(A.v, B3, acc[s][3], 0, 0, 0);
        }
      }
    }

    __syncthreads();                       // everyone done reading buffer pb
    if (g < 2) STAGE(g + 2, pb);           // refill it (stays in flight past barrier)
  }
#undef STAGE

  // epilogue: each wave owns its 32 rows; 16 window-blocks accumulate via atomics
  #pragma unroll
  for (int s = 0; s < 2; ++s)
    #pragma unroll
    for (int nf = 0; nf < 4; ++nf)
      #pragma unroll
      for (int r = 0; r < 4; ++r) {
        int row = i0 + s * 16 + q * 4 + r;
        int col = nf * 16 + m;
        atomicAdd(&out[row * 64 + col], 0.25f * acc[s][nf][r]);
      }
}

extern "C" void kernel_launch(void* const* d_in, const int* in_sizes, int n_in,
                              void* d_out, int out_size, void* d_ws, size_t ws_size,
                              hipStream_t stream) {
  const float* x   = (const float*)d_in[0];   // (4096, 256)
  const float* adj = (const float*)d_in[1];   // (4096, 4096)
  const float* W   = (const float*)d_in[2];   // (256, 256)
  const float* a   = (const float*)d_in[3];   // (128, 1)
  float* out = (float*)d_out;                 // (4096, 64)

  char* ws = (char*)d_ws;
  unsigned short* Vf = (unsigned short*)ws;                  // 2 MB  bf16 fragment-ordered
  float* el4   = (float*)(ws + (2u << 20));                  // 64 KB [4096][4]
  float* Qr    = (float*)(ws + (2u << 20) + (64u << 10));    // 64 KB [4][4096]
  float* Sr    = (float*)(ws + (2u << 20) + (128u << 10));   // 64 KB [4][4096]
  float* lsumP = (float*)(ws + (2u << 20) + (192u << 10));   // 256 KB [4][4096][4]
  unsigned long long* adjB = (unsigned long long*)(ws + (2u << 20) + (448u << 10)); // 2 MB bits

  hipMemsetAsync(out, 0, (size_t)out_size * sizeof(float), stream);
  k1_proj<<<512, 256, 0, stream>>>(x, W, a, Vf, el4, Qr, Sr);
  k0_pack<<<dim3(1024, 4), 256, 0, stream>>>(adj, el4, Qr, Sr, adjB, lsumP);
  k2_attn<<<dim3(32, 16), 256, 0, stream>>>(adjB, Vf, el4, lsumP, Qr, Sr, out);
}